// Round 1
// baseline (228.650 us; speedup 1.0000x reference)
//
#include <hip/hip_runtime.h>
#include <math.h>

// Problem constants (B=2, N=M=2048, d_model=1024, m_bits=32, d_head=64)
#define DM 1024
#define NB 2048        // rows per batch
#define NROWS 4096     // B*N
#define MBITS 32
#define DH 64

typedef __attribute__((ext_vector_type(4))) float floatx4;
typedef __attribute__((ext_vector_type(8))) short shortx8;

__device__ __forceinline__ unsigned short f32_to_bf16(float f) {
    union { float f; unsigned u; } v; v.f = f;
    unsigned r = v.u + 0x7FFF + ((v.u >> 16) & 1);   // round-to-nearest-even
    return (unsigned short)(r >> 16);
}

// ---------------------------------------------------------------------------
// Projection kernel: one fused launch, 256 blocks x 256 threads.
//  blocks   0..63 : Qt = Q @ Wq   (f32 out, [4096][32])
//  blocks  64..127: Kt = K @ Wk   (f32 out, [4096][32])
//  blocks 128..255: VpT = (V @ Wv)^T as bf16, [b][h][j]  (for MFMA B-frags)
// Block tile: 64 rows x 32 cols; thread tile 2r x 4c; k chunked by 64.
// ---------------------------------------------------------------------------
__global__ __launch_bounds__(256) void trop_proj_kernel(
    const float* __restrict__ Q, const float* __restrict__ K, const float* __restrict__ V,
    const float* __restrict__ Wq, const float* __restrict__ Wk, const float* __restrict__ Wv,
    float* __restrict__ Qt, float* __restrict__ Kt, unsigned short* __restrict__ VpT)
{
    __shared__ float Xs[64][68];   // 64 rows x 64 k, pad 68 (272B rows, 16B aligned)
    __shared__ float Ws[32][68];   // transposed W chunk: [c][k]

    int bx = blockIdx.x;
    const float* X; const float* W; int C, c0, job, rb;
    if (bx < 64)       { job = 0; rb = bx;        X = Q; W = Wq; C = 32; c0 = 0; }
    else if (bx < 128) { job = 1; rb = bx - 64;   X = K; W = Wk; C = 32; c0 = 0; }
    else { job = 2; int z = bx - 128; rb = z >> 1; X = V; W = Wv; C = 64; c0 = (z & 1) * 32; }
    int r0 = rb * 64;
    int t  = threadIdx.x;
    int rg = t >> 3;   // 0..31 -> rows 2rg, 2rg+1
    int cg = t & 7;    // 0..7  -> cols cg + 8*ci

    float acc[2][4] = {{0,0,0,0},{0,0,0,0}};

    for (int kc = 0; kc < 16; ++kc) {
        __syncthreads();
        // stage X chunk: 64 rows x 64 k  (1024 float4, 4 per thread, coalesced)
        #pragma unroll
        for (int u = 0; u < 4; ++u) {
            int flat4 = u * 256 + t;
            int row = flat4 >> 4;        // 0..63
            int c4  = flat4 & 15;        // 0..15
            floatx4 g = *(const floatx4*)&X[(size_t)(r0 + row) * DM + kc * 64 + c4 * 4];
            *(floatx4*)&Xs[row][c4 * 4] = g;
        }
        // stage W chunk transposed: Ws[c][k] for 64 k x 32 c
        #pragma unroll
        for (int u = 0; u < 2; ++u) {
            int flat4 = u * 256 + t;
            int k  = flat4 >> 3;         // 0..63
            int c4 = flat4 & 7;          // 0..7
            floatx4 g = *(const floatx4*)&W[(size_t)(kc * 64 + k) * C + c0 + c4 * 4];
            Ws[c4 * 4 + 0][k] = g.x;
            Ws[c4 * 4 + 1][k] = g.y;
            Ws[c4 * 4 + 2][k] = g.z;
            Ws[c4 * 4 + 3][k] = g.w;
        }
        __syncthreads();
        #pragma unroll
        for (int k4 = 0; k4 < 16; ++k4) {
            floatx4 x0 = *(const floatx4*)&Xs[2 * rg + 0][k4 * 4];
            floatx4 x1 = *(const floatx4*)&Xs[2 * rg + 1][k4 * 4];
            #pragma unroll
            for (int ci = 0; ci < 4; ++ci) {
                floatx4 w4 = *(const floatx4*)&Ws[cg + 8 * ci][k4 * 4];
                acc[0][ci] += x0.x * w4.x + x0.y * w4.y + x0.z * w4.z + x0.w * w4.w;
                acc[1][ci] += x1.x * w4.x + x1.y * w4.y + x1.z * w4.z + x1.w * w4.w;
            }
        }
    }

    if (job < 2) {
        float* Y = (job == 0) ? Qt : Kt;
        #pragma unroll
        for (int ri = 0; ri < 2; ++ri)
            #pragma unroll
            for (int ci = 0; ci < 4; ++ci)
                Y[(size_t)(r0 + 2 * rg + ri) * MBITS + cg + 8 * ci] = acc[ri][ci];
    } else {
        // VpT[b][h][j] bf16; rows r0+2rg (+1) are j-adjacent in one batch
        int r = r0 + 2 * rg;
        int b = r >> 11, j = r & 2047;
        #pragma unroll
        for (int ci = 0; ci < 4; ++ci) {
            int h = c0 + cg + 8 * ci;
            unsigned pack = (unsigned)f32_to_bf16(acc[0][ci])
                          | ((unsigned)f32_to_bf16(acc[1][ci]) << 16);
            *(unsigned*)&VpT[(size_t)b * (DH * NB) + (size_t)h * NB + j] = pack;
        }
    }
}

// ---------------------------------------------------------------------------
// Pass 1: rowsums of exp(scores). Grid (128, B), 256 threads.
// Block = 16 rows x full M sweep in 256-col tiles. Thread tile 4i x 4j.
// ---------------------------------------------------------------------------
__global__ __launch_bounds__(256) void trop_pass1_kernel(
    const float* __restrict__ Qt, const float* __restrict__ Kt,
    const float* __restrict__ temp, float* __restrict__ rowsum)
{
    __shared__ float Qs[16][36];
    __shared__ float Ks[256][36];

    int b  = blockIdx.y;
    int i0 = blockIdx.x * 16;
    int t  = threadIdx.x;
    int w  = t >> 6, l = t & 63;

    if (t < 128) {
        int row = t >> 3, k4 = t & 7;
        *(floatx4*)&Qs[row][k4 * 4] =
            *(const floatx4*)&Qt[(size_t)(b * NB + i0 + row) * MBITS + k4 * 4];
    }
    float tv = temp[0];
    float c2 = -(1.0f / log1pf(__expf(tv))) * 1.44269504088896340736f;

    float psum[4] = {0, 0, 0, 0};

    for (int jc = 0; jc < 8; ++jc) {
        __syncthreads();
        #pragma unroll
        for (int u = 0; u < 8; ++u) {
            int flat4 = u * 256 + t;
            int row = flat4 >> 3, k4 = flat4 & 7;
            *(floatx4*)&Ks[row][k4 * 4] =
                *(const floatx4*)&Kt[(size_t)(b * NB + jc * 256 + row) * MBITS + k4 * 4];
        }
        __syncthreads();

        float m[4][4];
        #pragma unroll
        for (int ii = 0; ii < 4; ++ii)
            #pragma unroll
            for (int jj = 0; jj < 4; ++jj) m[ii][jj] = 1e30f;

        #pragma unroll
        for (int k4 = 0; k4 < 8; ++k4) {
            floatx4 q[4], kk[4];
            #pragma unroll
            for (int ii = 0; ii < 4; ++ii) q[ii] = *(const floatx4*)&Qs[w + 4 * ii][k4 * 4];
            #pragma unroll
            for (int jj = 0; jj < 4; ++jj) kk[jj] = *(const floatx4*)&Ks[l + 64 * jj][k4 * 4];
            #pragma unroll
            for (int ii = 0; ii < 4; ++ii)
                #pragma unroll
                for (int jj = 0; jj < 4; ++jj) {
                    float a0 = q[ii].x + kk[jj].x;
                    float a1 = q[ii].y + kk[jj].y;
                    float a2 = q[ii].z + kk[jj].z;
                    float a3 = q[ii].w + kk[jj].w;
                    m[ii][jj] = fminf(m[ii][jj], fminf(fminf(a0, a1), fminf(a2, a3)));
                }
        }
        #pragma unroll
        for (int ii = 0; ii < 4; ++ii)
            #pragma unroll
            for (int jj = 0; jj < 4; ++jj)
                psum[ii] += exp2f(c2 * m[ii][jj]);
    }

    // wave-level reduction (all 64 lanes of wave w share the same 4 i's)
    #pragma unroll
    for (int ii = 0; ii < 4; ++ii) {
        float v = psum[ii];
        #pragma unroll
        for (int off = 1; off < 64; off <<= 1) v += __shfl_xor(v, off, 64);
        if (l == 0) rowsum[(size_t)b * NB + i0 + w + 4 * ii] = v;
    }
}

// ---------------------------------------------------------------------------
// Pass 2: recompute e, write normalized attn, accumulate out via bf16 MFMA.
// Grid (128, B), 256 threads (4 waves; wave w owns h-slice w*16..w*16+15).
// ---------------------------------------------------------------------------
__global__ __launch_bounds__(256) void trop_pass2_kernel(
    const float* __restrict__ Qt, const float* __restrict__ Kt,
    const unsigned short* __restrict__ VpT,
    const float* __restrict__ temp, const float* __restrict__ rowsum,
    float* __restrict__ outp, float* __restrict__ attn)
{
    __shared__ float Qs[16][36];
    __shared__ float Ks[256][36];
    __shared__ unsigned short Vs[64][256];   // B-operand tiles, XOR-swizzled 16B chunks
    __shared__ unsigned short Es[16][264];   // A-operand (unnormalized e, bf16)
    __shared__ float inv_s[16];

    int b  = blockIdx.y;
    int i0 = blockIdx.x * 16;
    int t  = threadIdx.x;
    int w  = t >> 6, l = t & 63;

    if (t < 128) {
        int row = t >> 3, k4 = t & 7;
        *(floatx4*)&Qs[row][k4 * 4] =
            *(const floatx4*)&Qt[(size_t)(b * NB + i0 + row) * MBITS + k4 * 4];
    }
    if (t < 16) inv_s[t] = 1.0f / rowsum[(size_t)b * NB + i0 + t];

    float tv = temp[0];
    float c2 = -(1.0f / log1pf(__expf(tv))) * 1.44269504088896340736f;

    floatx4 acc = {0.f, 0.f, 0.f, 0.f};
    __syncthreads();

    float inv_i[4];
    #pragma unroll
    for (int ii = 0; ii < 4; ++ii) inv_i[ii] = inv_s[w + 4 * ii];

    for (int jc = 0; jc < 8; ++jc) {
        // stage K tile (coalesced) and V tile (pre-transposed bf16, coalesced b128)
        #pragma unroll
        for (int u = 0; u < 8; ++u) {
            int flat4 = u * 256 + t;
            int row = flat4 >> 3, k4 = flat4 & 7;
            *(floatx4*)&Ks[row][k4 * 4] =
                *(const floatx4*)&Kt[(size_t)(b * NB + jc * 256 + row) * MBITS + k4 * 4];
        }
        #pragma unroll
        for (int u = 0; u < 8; ++u) {
            int flat16 = u * 256 + t;
            int h = flat16 >> 5, c = flat16 & 31;   // 64 h-rows x 32 16B-chunks
            uint4 g = *(const uint4*)&VpT[(size_t)b * (DH * NB) + (size_t)h * NB + jc * 256 + c * 8];
            *(uint4*)&Vs[h][(c ^ (h & 31)) * 8] = g;
        }
        __syncthreads();

        float m[4][4];
        #pragma unroll
        for (int ii = 0; ii < 4; ++ii)
            #pragma unroll
            for (int jj = 0; jj < 4; ++jj) m[ii][jj] = 1e30f;

        #pragma unroll
        for (int k4 = 0; k4 < 8; ++k4) {
            floatx4 q[4], kk[4];
            #pragma unroll
            for (int ii = 0; ii < 4; ++ii) q[ii] = *(const floatx4*)&Qs[w + 4 * ii][k4 * 4];
            #pragma unroll
            for (int jj = 0; jj < 4; ++jj) kk[jj] = *(const floatx4*)&Ks[l + 64 * jj][k4 * 4];
            #pragma unroll
            for (int ii = 0; ii < 4; ++ii)
                #pragma unroll
                for (int jj = 0; jj < 4; ++jj) {
                    float a0 = q[ii].x + kk[jj].x;
                    float a1 = q[ii].y + kk[jj].y;
                    float a2 = q[ii].z + kk[jj].z;
                    float a3 = q[ii].w + kk[jj].w;
                    m[ii][jj] = fminf(m[ii][jj], fminf(fminf(a0, a1), fminf(a2, a3)));
                }
        }

        // e, attn stores (fully coalesced: 64 consecutive floats per instr), Es bf16
        #pragma unroll
        for (int ii = 0; ii < 4; ++ii) {
            int i = w + 4 * ii;
            #pragma unroll
            for (int jj = 0; jj < 4; ++jj) {
                int j = l + 64 * jj;
                float e = exp2f(c2 * m[ii][jj]);
                attn[(size_t)(b * NB + i0 + i) * 2048 + jc * 256 + j] = e * inv_i[ii];
                Es[i][j] = f32_to_bf16(e);
            }
        }
        __syncthreads();

        // out += Es (A-layout) x Vs (B-layout), k = 256 per tile
        #pragma unroll
        for (int kk = 0; kk < 8; ++kk) {
            int mrow = l & 15, q4 = l >> 4;
            shortx8 a = *(const shortx8*)&Es[mrow][kk * 32 + q4 * 8];
            int h = w * 16 + mrow;
            int c = kk * 4 + q4;
            shortx8 bf = *(const shortx8*)&Vs[h][(c ^ (h & 31)) * 8];
            acc = __builtin_amdgcn_mfma_f32_16x16x32_bf16(a, bf, acc, 0, 0, 0);
        }
        __syncthreads();
    }

    // epilogue: C/D layout col=lane&15 (h), row=(lane>>4)*4+reg (i); scale by 1/rowsum
    #pragma unroll
    for (int r = 0; r < 4; ++r) {
        int irow = (l >> 4) * 4 + r;
        float v = acc[r] * inv_s[irow];
        outp[(size_t)(b * NB + i0 + irow) * DH + w * 16 + (l & 15)] = v;
    }
}

// ---------------------------------------------------------------------------
extern "C" void kernel_launch(void* const* d_in, const int* in_sizes, int n_in,
                              void* d_out, int out_size, void* d_ws, size_t ws_size,
                              hipStream_t stream) {
    (void)in_sizes; (void)n_in; (void)out_size; (void)ws_size;
    const float* Q    = (const float*)d_in[0];
    const float* K    = (const float*)d_in[1];
    const float* V    = (const float*)d_in[2];
    const float* Wq   = (const float*)d_in[3];
    const float* Wk   = (const float*)d_in[4];
    const float* Wv   = (const float*)d_in[5];
    const float* temp = (const float*)d_in[6];

    float* outp = (float*)d_out;                 // [2][2048][64]
    float* attn = outp + 2 * 2048 * 64;          // [2][2048][2048]

    float* wsf = (float*)d_ws;
    float* Qt      = wsf;                        // 131072 f32
    float* Kt      = wsf + 131072;               // 131072 f32
    float* rowsum  = wsf + 262144;               // 4096 f32
    unsigned short* VpT = (unsigned short*)(wsf + 266240);  // 262144 bf16

    trop_proj_kernel<<<256, 256, 0, stream>>>(Q, K, V, Wq, Wk, Wv, Qt, Kt, VpT);
    trop_pass1_kernel<<<dim3(128, 2), 256, 0, stream>>>(Qt, Kt, temp, rowsum);
    trop_pass2_kernel<<<dim3(128, 2), 256, 0, stream>>>(Qt, Kt, VpT, temp, rowsum, outp, attn);
}

// Round 2
// 164.708 us; speedup vs baseline: 1.3882x; 1.3882x over previous
//
#include <hip/hip_runtime.h>
#include <math.h>

// Problem constants (B=2, N=M=2048, d_model=1024, m_bits=32, d_head=64)
#define DM 1024
#define NB 2048        // rows per batch
#define MBITS 32
#define DH 64

typedef __attribute__((ext_vector_type(4))) float floatx4;
typedef __attribute__((ext_vector_type(8))) short shortx8;

__device__ __forceinline__ unsigned short f32_to_bf16(float f) {
    union { float f; unsigned u; } v; v.f = f;
    unsigned r = v.u + 0x7FFF + ((v.u >> 16) & 1);   // round-to-nearest-even
    return (unsigned short)(r >> 16);
}

// ---------------------------------------------------------------------------
// Projection kernel, split-k x4 with f32 atomic accumulation.
// grid (256, 4) x 256 threads. blockIdx.x = tile job, blockIdx.y = k-quarter.
//  jobs   0..63 : Qt += Q @ Wq [4096][32]
//  jobs  64..127: Kt += K @ Wk [4096][32]
//  jobs 128..255: Vp += V @ Wv [4096][64] (two 32-col halves)
// Tile 64 rows x 32 cols, thread 2r x 4c, k chunked by 64 (4 chunks/block).
// ---------------------------------------------------------------------------
__global__ __launch_bounds__(256) void trop_proj_kernel(
    const float* __restrict__ Q, const float* __restrict__ K, const float* __restrict__ V,
    const float* __restrict__ Wq, const float* __restrict__ Wk, const float* __restrict__ Wv,
    float* __restrict__ Qt, float* __restrict__ Kt, float* __restrict__ Vp)
{
    __shared__ float Xs[64][68];
    __shared__ float Ws[32][68];

    int bx = blockIdx.x, kq = blockIdx.y;
    const float* X; const float* W; int C, c0, job, rb;
    if (bx < 64)       { job = 0; rb = bx;        X = Q; W = Wq; C = 32; c0 = 0; }
    else if (bx < 128) { job = 1; rb = bx - 64;   X = K; W = Wk; C = 32; c0 = 0; }
    else { job = 2; int z = bx - 128; rb = z >> 1; X = V; W = Wv; C = 64; c0 = (z & 1) * 32; }
    int r0 = rb * 64;
    int t  = threadIdx.x;
    int rg = t >> 3;   // 0..31 -> rows 2rg, 2rg+1
    int cg = t & 7;    // 0..7  -> cols cg + 8*ci

    float acc[2][4] = {{0,0,0,0},{0,0,0,0}};

    for (int kc = kq * 4; kc < kq * 4 + 4; ++kc) {
        __syncthreads();
        #pragma unroll
        for (int u = 0; u < 4; ++u) {
            int flat4 = u * 256 + t;
            int row = flat4 >> 4, c4 = flat4 & 15;
            floatx4 g = *(const floatx4*)&X[(size_t)(r0 + row) * DM + kc * 64 + c4 * 4];
            *(floatx4*)&Xs[row][c4 * 4] = g;
        }
        #pragma unroll
        for (int u = 0; u < 2; ++u) {
            int flat4 = u * 256 + t;
            int k = flat4 >> 3, c4 = flat4 & 7;
            floatx4 g = *(const floatx4*)&W[(size_t)(kc * 64 + k) * C + c0 + c4 * 4];
            Ws[c4 * 4 + 0][k] = g.x;
            Ws[c4 * 4 + 1][k] = g.y;
            Ws[c4 * 4 + 2][k] = g.z;
            Ws[c4 * 4 + 3][k] = g.w;
        }
        __syncthreads();
        #pragma unroll
        for (int k4 = 0; k4 < 16; ++k4) {
            floatx4 x0 = *(const floatx4*)&Xs[2 * rg + 0][k4 * 4];
            floatx4 x1 = *(const floatx4*)&Xs[2 * rg + 1][k4 * 4];
            #pragma unroll
            for (int ci = 0; ci < 4; ++ci) {
                floatx4 w4 = *(const floatx4*)&Ws[cg + 8 * ci][k4 * 4];
                acc[0][ci] += x0.x * w4.x + x0.y * w4.y + x0.z * w4.z + x0.w * w4.w;
                acc[1][ci] += x1.x * w4.x + x1.y * w4.y + x1.z * w4.z + x1.w * w4.w;
            }
        }
    }

    float* Y = (job == 0) ? Qt : (job == 1) ? Kt : Vp;
    int Cout = (job == 2) ? 64 : 32;
    #pragma unroll
    for (int ri = 0; ri < 2; ++ri)
        #pragma unroll
        for (int ci = 0; ci < 4; ++ci)
            atomicAdd(&Y[(size_t)(r0 + 2 * rg + ri) * Cout + c0 + cg + 8 * ci], acc[ri][ci]);
}

// ---------------------------------------------------------------------------
// Vp [4096][64] f32 -> VpT [b][h][j] bf16 transpose. grid 128 x 256.
// ---------------------------------------------------------------------------
__global__ __launch_bounds__(256) void vp_transpose_kernel(
    const float* __restrict__ Vp, unsigned short* __restrict__ VpT)
{
    __shared__ float Ls[32][68];
    int r0 = blockIdx.x * 32;
    int t  = threadIdx.x;
    #pragma unroll
    for (int u = 0; u < 2; ++u) {
        int flat4 = u * 256 + t;
        int row = flat4 >> 4, c4 = flat4 & 15;
        *(floatx4*)&Ls[row][c4 * 4] = *(const floatx4*)&Vp[(size_t)(r0 + row) * DH + c4 * 4];
    }
    __syncthreads();
    int b = r0 >> 11, j0 = r0 & 2047;
    #pragma unroll
    for (int u = 0; u < 8; ++u) {
        int flat = u * 256 + t;
        int h = flat >> 5, j = flat & 31;
        VpT[(size_t)b * (DH * NB) + (size_t)h * NB + j0 + j] = f32_to_bf16(Ls[j][h]);
    }
}

// ---------------------------------------------------------------------------
// Score pass: tropical min-plus scores, unnormalized e -> attn region,
// per-(row, j-chunk) partial sums. grid (128, 8, 2) x 256 threads.
// Block = 16 rows x 256 j. Thread tile 4i x 4j. LDS ~39 KB -> 4 blocks/CU.
// ---------------------------------------------------------------------------
__global__ __launch_bounds__(256) void trop_score_kernel(
    const float* __restrict__ Qt, const float* __restrict__ Kt,
    const float* __restrict__ temp, float* __restrict__ partial,
    float* __restrict__ attn)
{
    __shared__ float Qs[16][36];
    __shared__ float Ks[256][36];

    int b  = blockIdx.z;
    int jc = blockIdx.y;
    int i0 = blockIdx.x * 16;
    int t  = threadIdx.x;
    int w  = t >> 6, l = t & 63;

    if (t < 128) {
        int row = t >> 3, k4 = t & 7;
        *(floatx4*)&Qs[row][k4 * 4] =
            *(const floatx4*)&Qt[(size_t)(b * NB + i0 + row) * MBITS + k4 * 4];
    }
    #pragma unroll
    for (int u = 0; u < 8; ++u) {
        int flat4 = u * 256 + t;
        int row = flat4 >> 3, k4 = flat4 & 7;
        *(floatx4*)&Ks[row][k4 * 4] =
            *(const floatx4*)&Kt[(size_t)(b * NB + jc * 256 + row) * MBITS + k4 * 4];
    }
    float tv = temp[0];
    float c2 = -(1.0f / log1pf(__expf(tv))) * 1.44269504088896340736f;
    __syncthreads();

    float m[4][4];
    #pragma unroll
    for (int ii = 0; ii < 4; ++ii)
        #pragma unroll
        for (int jj = 0; jj < 4; ++jj) m[ii][jj] = 1e30f;

    #pragma unroll
    for (int k4 = 0; k4 < 8; ++k4) {
        floatx4 q[4], kk[4];
        #pragma unroll
        for (int ii = 0; ii < 4; ++ii) q[ii] = *(const floatx4*)&Qs[w + 4 * ii][k4 * 4];
        #pragma unroll
        for (int jj = 0; jj < 4; ++jj) kk[jj] = *(const floatx4*)&Ks[l + 64 * jj][k4 * 4];
        #pragma unroll
        for (int ii = 0; ii < 4; ++ii)
            #pragma unroll
            for (int jj = 0; jj < 4; ++jj) {
                float a0 = q[ii].x + kk[jj].x;
                float a1 = q[ii].y + kk[jj].y;
                float a2 = q[ii].z + kk[jj].z;
                float a3 = q[ii].w + kk[jj].w;
                m[ii][jj] = fminf(m[ii][jj], fminf(fminf(a0, a1), fminf(a2, a3)));
            }
    }

    float psum[4];
    #pragma unroll
    for (int ii = 0; ii < 4; ++ii) {
        int i = w + 4 * ii;
        float s = 0.f;
        #pragma unroll
        for (int jj = 0; jj < 4; ++jj) {
            int j = l + 64 * jj;
            float e = exp2f(c2 * m[ii][jj]);
            attn[(size_t)(b * NB + i0 + i) * 2048 + jc * 256 + j] = e;  // unnormalized
            s += e;
        }
        psum[ii] = s;
    }

    #pragma unroll
    for (int ii = 0; ii < 4; ++ii) {
        float v = psum[ii];
        #pragma unroll
        for (int off = 1; off < 64; off <<= 1) v += __shfl_xor(v, off, 64);
        if (l == 0) partial[((size_t)b * NB + i0 + w + 4 * ii) * 8 + jc] = v;
    }
}

// ---------------------------------------------------------------------------
// Out pass: normalize attn in place, out += attn_tile @ Vp via bf16 MFMA.
// grid (128, 8, 2) x 256 threads. Block = 16 rows x 256 j. LDS ~41 KB.
// ---------------------------------------------------------------------------
__global__ __launch_bounds__(256) void trop_out_kernel(
    const unsigned short* __restrict__ VpT, const float* __restrict__ partial,
    float* __restrict__ outp, float* __restrict__ attn)
{
    __shared__ unsigned short Vs[64][256];   // B-operand, XOR-swizzled 16B chunks
    __shared__ unsigned short Es[16][264];   // A-operand (normalized attn, bf16)
    __shared__ float inv_s[16];

    int b  = blockIdx.z;
    int jc = blockIdx.y;
    int i0 = blockIdx.x * 16;
    int t  = threadIdx.x;
    int w  = t >> 6, l = t & 63;

    #pragma unroll
    for (int u = 0; u < 8; ++u) {
        int flat16 = u * 256 + t;
        int h = flat16 >> 5, c = flat16 & 31;
        uint4 g = *(const uint4*)&VpT[(size_t)b * (DH * NB) + (size_t)h * NB + jc * 256 + c * 8];
        *(uint4*)&Vs[h][(c ^ (h & 31)) * 8] = g;
    }
    if (t < 16) {
        float s = 0.f;
        #pragma unroll
        for (int p = 0; p < 8; ++p) s += partial[((size_t)b * NB + i0 + t) * 8 + p];
        inv_s[t] = 1.0f / s;
    }
    __syncthreads();

    // normalize in place + populate Es (bf16)
    #pragma unroll
    for (int u = 0; u < 4; ++u) {
        int flat4 = u * 256 + t;
        int row = flat4 >> 6, c4 = flat4 & 63;
        size_t g = (size_t)(b * NB + i0 + row) * 2048 + jc * 256 + c4 * 4;
        floatx4 e4 = *(const floatx4*)&attn[g];
        float iv = inv_s[row];
        e4.x *= iv; e4.y *= iv; e4.z *= iv; e4.w *= iv;
        *(floatx4*)&attn[g] = e4;
        unsigned u0 = (unsigned)f32_to_bf16(e4.x) | ((unsigned)f32_to_bf16(e4.y) << 16);
        unsigned u1 = (unsigned)f32_to_bf16(e4.z) | ((unsigned)f32_to_bf16(e4.w) << 16);
        uint2 pk; pk.x = u0; pk.y = u1;
        *(uint2*)&Es[row][c4 * 4] = pk;
    }
    __syncthreads();

    floatx4 acc = {0.f, 0.f, 0.f, 0.f};
    #pragma unroll
    for (int kk = 0; kk < 8; ++kk) {
        int mrow = l & 15, q4 = l >> 4;
        shortx8 a = *(const shortx8*)&Es[mrow][kk * 32 + q4 * 8];
        int h = w * 16 + mrow;
        int c = kk * 4 + q4;
        shortx8 bf = *(const shortx8*)&Vs[h][(c ^ (h & 31)) * 8];
        acc = __builtin_amdgcn_mfma_f32_16x16x32_bf16(a, bf, acc, 0, 0, 0);
    }

    // C/D layout: col=lane&15 (h), row=(lane>>4)*4+reg (i)
    #pragma unroll
    for (int r = 0; r < 4; ++r) {
        int irow = (l >> 4) * 4 + r;
        atomicAdd(&outp[(size_t)(b * NB + i0 + irow) * DH + w * 16 + (l & 15)], acc[r]);
    }
}

// ---------------------------------------------------------------------------
extern "C" void kernel_launch(void* const* d_in, const int* in_sizes, int n_in,
                              void* d_out, int out_size, void* d_ws, size_t ws_size,
                              hipStream_t stream) {
    (void)in_sizes; (void)n_in; (void)out_size; (void)ws_size;
    const float* Q    = (const float*)d_in[0];
    const float* K    = (const float*)d_in[1];
    const float* V    = (const float*)d_in[2];
    const float* Wq   = (const float*)d_in[3];
    const float* Wk   = (const float*)d_in[4];
    const float* Wv   = (const float*)d_in[5];
    const float* temp = (const float*)d_in[6];

    float* outp = (float*)d_out;                 // [2][2048][64]
    float* attn = outp + 2 * 2048 * 64;          // [2][2048][2048]

    float* wsf = (float*)d_ws;
    float* Qt      = wsf;                          // 131072 f32 (512 KB)
    float* Kt      = wsf + 131072;                 // 131072 f32 (512 KB)
    float* Vp      = wsf + 262144;                 // 262144 f32 (1 MB)
    float* partial = wsf + 524288;                 // 32768 f32 (128 KB)
    unsigned short* VpT = (unsigned short*)(wsf + 557056);  // 262144 bf16 (512 KB)

    // zero atomic-accumulated buffers (Qt,Kt,Vp contiguous; out)
    hipMemsetAsync(d_ws, 0, 524288 * sizeof(float), stream);
    hipMemsetAsync(d_out, 0, 262144 * sizeof(float), stream);

    trop_proj_kernel<<<dim3(256, 4), 256, 0, stream>>>(Q, K, V, Wq, Wk, Wv, Qt, Kt, Vp);
    vp_transpose_kernel<<<128, 256, 0, stream>>>(Vp, VpT);
    trop_score_kernel<<<dim3(128, 8, 2), 256, 0, stream>>>(Qt, Kt, temp, partial, attn);
    trop_out_kernel<<<dim3(128, 8, 2), 256, 0, stream>>>(VpT, partial, outp, attn);
}